// Round 7
// baseline (564.467 us; speedup 1.0000x reference)
//
#include <hip/hip_runtime.h>
#include <hip/hip_bf16.h>
#include <math.h>

#define BATCH  2
#define SEQ    2048
#define HID    1024
#define INNER  2048
#define NSTATE 64
#define NTOK   (BATCH * SEQ)
#define TCHUNK 64
#define NCHUNK (SEQ / TCHUNK)

typedef __bf16 bf16x8 __attribute__((ext_vector_type(8)));
typedef float  f32x4  __attribute__((ext_vector_type(4)));

typedef const __attribute__((address_space(1))) char* gas_ptr;
typedef __attribute__((address_space(3))) char*       las_ptr;

__device__ __forceinline__ void gload16(const void* g, void* l) {
  __builtin_amdgcn_global_load_lds((gas_ptr)g, (las_ptr)l, 16, 0, 0);
}

__device__ __forceinline__ unsigned short f2bf(float f) {
  __hip_bfloat16 h = __float2bfloat16(f);
  return __builtin_bit_cast(unsigned short, h);
}
__device__ __forceinline__ float bf2f(unsigned short u) {
  unsigned int x = ((unsigned int)u) << 16;
  return __builtin_bit_cast(float, x);
}

// ---------------------------------------------------------------- cvt fp32->bf16
__global__ __launch_bounds__(256) void cvt_f32_bf16_kernel(
    const float* __restrict__ in, __hip_bfloat16* __restrict__ out, int n4) {
  int i = blockIdx.x * 256 + threadIdx.x;
  if (i >= n4) return;
  float4 v = ((const float4*)in)[i];
  ushort4 u;
  u.x = f2bf(v.x); u.y = f2bf(v.y); u.z = f2bf(v.z); u.w = f2bf(v.w);
  ((ushort4*)out)[i] = u;
}

// ------------------------------------------------- transpose fp32 [R][C] -> bf16 [C][ostride]
__global__ __launch_bounds__(256) void transpose_cvt_kernel(
    const float* __restrict__ in, __hip_bfloat16* __restrict__ out,
    int R, int C, int ostride) {
  __shared__ float tile[32][33];
  int tx = threadIdx.x & 31, ty = threadIdx.x >> 5;
  int c0 = blockIdx.x * 32, r0 = blockIdx.y * 32;
#pragma unroll
  for (int i = 0; i < 4; ++i)
    tile[ty + 8 * i][tx] = in[(size_t)(r0 + ty + 8 * i) * C + c0 + tx];
  __syncthreads();
#pragma unroll
  for (int i = 0; i < 4; ++i)
    out[(size_t)(c0 + ty + 8 * i) * ostride + r0 + tx] =
        __float2bfloat16(tile[tx][ty + 8 * i]);
}

// ---------------------------------------------------------------- 256x256 8-phase GEMM
// C[M,N] = A[M,K] x Bt[N,K].  8 waves (2M x 4N), BK=64, 128KB LDS (2 tile-slots),
// 1-tile-ahead prefetch via global_load_lds, counted vmcnt(2), st-swizzled LDS.
// EPI 0: fp32 -> Cout (ldc). EPI 1: bf16 split xin|z. EPI 2: dt|Bm|Cm (guarded, N padded).
__device__ __forceinline__ void stage_half(
    const __hip_bfloat16* __restrict__ gb, int rbase, int K, int t,
    char* sm, int matOff, int e, int h, int w, int lane) {
#pragma unroll
  for (int l = 0; l < 2; ++l) {
    const int X = (w * 2 + l) * 1024 + lane * 16;
    const int Xs = X ^ (((X >> 9) & 1) << 5);
    const int rr = Xs >> 7, cb = Xs & 127;
    const char* gsrc = (const char*)(gb + (size_t)(rbase + rr) * K + (size_t)t * 64) + cb;
    char* ldst = sm + matOff + e * 32768 + h * 16384 + (w * 2 + l) * 1024;
    gload16(gsrc, ldst);
  }
}

#define MF(i, j, av, bv) \
  acc[i][j] = __builtin_amdgcn_mfma_f32_16x16x32_bf16(av, bv, acc[i][j], 0, 0, 0)
#define MFROW(i, as0, as1)                      \
  MF(i, 0, as0, b00); MF(i, 0, as1, b01);       \
  MF(i, 1, as0, b10); MF(i, 1, as1, b11);       \
  MF(i, 2, as0, b20); MF(i, 2, as1, b21);       \
  MF(i, 3, as0, b30); MF(i, 3, as1, b31)

template <int EPI>
__global__ __launch_bounds__(512, 2) void gemm8p_kernel(
    const __hip_bfloat16* __restrict__ A, const __hip_bfloat16* __restrict__ Bt,
    int M, int N, int K, int gridN, int nwg,
    float* __restrict__ Cout, int ldc,
    const float* __restrict__ bdt,
    __hip_bfloat16* __restrict__ o0, __hip_bfloat16* __restrict__ o1,
    float* __restrict__ f0, float* __restrict__ f1, float* __restrict__ f2) {
  __shared__ __align__(128) char sm[131072];
  const int tid = threadIdx.x;
  const int lane = tid & 63;
  const int w = tid >> 6;
  const int wr = w >> 2;        // M-half (0/1): rows wr*128..+128
  const int wcq = w & 3;        // N-quarter: cols wcq*64..+64
  const int lrow = lane & 15, lk = lane >> 4;

  // bijective XCD swizzle (m204)
  const int orig = blockIdx.x;
  const int q8 = nwg >> 3, r8 = nwg & 7;
  const int xcd = orig & 7, seq = orig >> 3;
  const int wg = (xcd < r8 ? xcd * (q8 + 1) : r8 * (q8 + 1) + (xcd - r8) * q8) + seq;
  const int m0 = (wg / gridN) * 256;
  const int n0 = (wg % gridN) * 256;

  f32x4 acc[8][4];
#pragma unroll
  for (int i = 0; i < 8; ++i)
#pragma unroll
    for (int j = 0; j < 4; ++j)
#pragma unroll
      for (int r = 0; r < 4; ++r) acc[i][j][r] = 0.f;

  const int NT = K >> 6;
  const int brow0 = (wcq & 1) * 64;

  // prologue: stage tile 0 into slot 0
  stage_half(A,  m0,       K, 0, sm, 0,     0, 0, w, lane);
  stage_half(A,  m0 + 128, K, 0, sm, 0,     0, 1, w, lane);
  stage_half(Bt, n0,       K, 0, sm, 65536, 0, 0, w, lane);
  stage_half(Bt, n0 + 128, K, 0, sm, 65536, 0, 1, w, lane);

  for (int t = 0; t < NT; ++t) {
    const int d = t & 1, e = d ^ 1;
    const bool pf = (t + 1 < NT);
    const char* aB = sm + d * 32768 + wr * 16384;
    const char* bB = sm + 65536 + d * 32768 + (wcq >> 1) * 16384;
    auto lda = [&](int ii, int ss) -> bf16x8 {
      int L = ((ii * 16 + lrow) * 128) + ss * 64 + lk * 16;
      L ^= ((L >> 9) & 1) << 5;
      return *(const bf16x8*)(aB + L);
    };
    auto ldb = [&](int jj, int ss) -> bf16x8 {
      int L = ((brow0 + jj * 16 + lrow) * 128) + ss * 64 + lk * 16;
      L ^= ((L >> 9) & 1) << 5;
      return *(const bf16x8*)(bB + L);
    };

    // ---- phase 0: stage A-h0(t+1); wait tile t; B frags + quadrant 0
    if (pf) stage_half(A, m0, K, t + 1, sm, 0, e, 0, w, lane);
    if (pf) asm volatile("s_waitcnt vmcnt(2)" ::: "memory");
    else    asm volatile("s_waitcnt vmcnt(0)" ::: "memory");
    __builtin_amdgcn_sched_barrier(0);
    __builtin_amdgcn_s_barrier();  // tile t published in slot d
    bf16x8 b00 = ldb(0, 0), b01 = ldb(0, 1), b10 = ldb(1, 0), b11 = ldb(1, 1);
    bf16x8 b20 = ldb(2, 0), b21 = ldb(2, 1), b30 = ldb(3, 0), b31 = ldb(3, 1);
    {
      bf16x8 a00 = lda(0, 0), a01 = lda(0, 1), a10 = lda(1, 0), a11 = lda(1, 1);
      __builtin_amdgcn_s_setprio(1);
      MFROW(0, a00, a01);
      MFROW(1, a10, a11);
      __builtin_amdgcn_s_setprio(0);
    }
    __builtin_amdgcn_s_barrier();
    // ---- phases 1..3: quadrant q; stage half-tiles A-h1, B-h0, B-h1 of t+1
#pragma unroll
    for (int q = 1; q < 4; ++q) {
      bf16x8 a00 = lda(2 * q, 0), a01 = lda(2 * q, 1);
      bf16x8 a10 = lda(2 * q + 1, 0), a11 = lda(2 * q + 1, 1);
      if (pf) {
        if (q == 1)      stage_half(A,  m0 + 128, K, t + 1, sm, 0,     e, 1, w, lane);
        else if (q == 2) stage_half(Bt, n0,       K, t + 1, sm, 65536, e, 0, w, lane);
        else             stage_half(Bt, n0 + 128, K, t + 1, sm, 65536, e, 1, w, lane);
      }
      __builtin_amdgcn_s_barrier();
      __builtin_amdgcn_s_setprio(1);
      MFROW(2 * q,     a00, a01);
      MFROW(2 * q + 1, a10, a11);
      __builtin_amdgcn_s_setprio(0);
      __builtin_amdgcn_s_barrier();
    }
  }

  // ---- epilogue
#pragma unroll
  for (int i = 0; i < 8; ++i) {
#pragma unroll
    for (int j = 0; j < 4; ++j) {
#pragma unroll
      for (int r = 0; r < 4; ++r) {
        const int row = m0 + wr * 128 + i * 16 + lk * 4 + r;
        const int col = n0 + wcq * 64 + j * 16 + lrow;
        const float v = acc[i][j][r];
        if constexpr (EPI == 0) {
          Cout[(size_t)row * ldc + col] = v;
        } else if constexpr (EPI == 1) {
          if (col < INNER) o0[(size_t)row * INNER + col] = __float2bfloat16(v);
          else             o1[(size_t)row * INNER + (col - INNER)] = __float2bfloat16(v);
        } else {
          if (col < INNER) {
            const float vv = v + bdt[col];
            const float dt = (vv > 15.f) ? vv : log1pf(expf(vv));
            f0[(size_t)row * INNER + col] = dt;
          } else if (col < INNER + NSTATE) {
            f1[(size_t)row * NSTATE + (col - INNER)] = v;
          } else if (col < INNER + 2 * NSTATE) {
            f2[(size_t)row * NSTATE + (col - INNER - NSTATE)] = v;
          }
        }
      }
    }
  }
}

// ---------------------------------------------------------------- causal depthwise conv + silu (bf16 in, bf16 out)
__global__ __launch_bounds__(256) void conv_silu_kernel(
    const __hip_bfloat16* __restrict__ xin, const float* __restrict__ cw,
    const float* __restrict__ cb, __hip_bfloat16* __restrict__ xch) {
  int idx = blockIdx.x * 256 + threadIdx.x;  // NTOK * (INNER/4)
  int cg = idx & 511;
  int tok = idx >> 9;
  int c = cg * 4;
  int l = tok & (SEQ - 1);
  float wv[4][4];
#pragma unroll
  for (int i = 0; i < 4; ++i) {
    float4 w = *(const float4*)&cw[(c + i) * 4];
    wv[i][0] = w.x; wv[i][1] = w.y; wv[i][2] = w.z; wv[i][3] = w.w;
  }
  float4 bias = *(const float4*)&cb[c];
  float r0 = bias.x, r1 = bias.y, r2 = bias.z, r3 = bias.w;
#pragma unroll
  for (int k = 0; k < 4; ++k) {
    const int d = 3 - k;
    if (l >= d) {
      ushort4 xv = *(const ushort4*)&xin[(size_t)(tok - d) * INNER + c];
      r0 = fmaf(bf2f(xv.x), wv[0][k], r0);
      r1 = fmaf(bf2f(xv.y), wv[1][k], r1);
      r2 = fmaf(bf2f(xv.z), wv[2][k], r2);
      r3 = fmaf(bf2f(xv.w), wv[3][k], r3);
    }
  }
  r0 = r0 / (1.f + __expf(-r0));
  r1 = r1 / (1.f + __expf(-r1));
  r2 = r2 / (1.f + __expf(-r2));
  r3 = r3 / (1.f + __expf(-r3));
  ushort4 u;
  u.x = f2bf(r0); u.y = f2bf(r1); u.z = f2bf(r2); u.w = f2bf(r3);
  *(ushort4*)&xch[(size_t)tok * INNER + c] = u;
}

// ---------------------------------------------------------------- scan phase 1 (within-chunk states only)
__global__ __launch_bounds__(256) void scan_state_kernel(
    const float* __restrict__ dtb, const __hip_bfloat16* __restrict__ xch,
    const float* __restrict__ Bm,
    float* __restrict__ S, float* __restrict__ A_chunk) {
  __shared__ float Bsh[TCHUNK][64];
  const int b = blockIdx.z, chunk = blockIdx.y;
  const int c = blockIdx.x * 256 + threadIdx.x;
  const int t0 = chunk * TCHUNK;
  for (int i = threadIdx.x; i < TCHUNK * 16; i += 256) {
    const int row = i >> 4, q = i & 15;
    *(float4*)&Bsh[row][q * 4] =
        *(const float4*)&Bm[((size_t)(b * SEQ + t0 + row)) * NSTATE + q * 4];
  }
  __syncthreads();
  float s[64];
#pragma unroll
  for (int n = 0; n < 64; ++n) s[n] = 0.f;
  float p = 1.f;
  const size_t base = (size_t)(b * SEQ + t0) * INNER + c;
  for (int t = 0; t < TCHUNK; ++t) {
    const float dtv = dtb[base + (size_t)t * INNER];
    const float at = __expf(-dtv);
    const float xc = __bfloat162float(xch[base + (size_t)t * INNER]);
    const float ut = dtv * xc;
    p *= at;
#pragma unroll
    for (int q = 0; q < 16; ++q) {
      const float4 bv = *(const float4*)&Bsh[t][q * 4];
      s[4 * q + 0] = fmaf(at, s[4 * q + 0], ut * bv.x);
      s[4 * q + 1] = fmaf(at, s[4 * q + 1], ut * bv.y);
      s[4 * q + 2] = fmaf(at, s[4 * q + 2], ut * bv.z);
      s[4 * q + 3] = fmaf(at, s[4 * q + 3], ut * bv.w);
    }
  }
  const size_t sbase = ((size_t)(b * NCHUNK + chunk) * INNER + c) * NSTATE;
#pragma unroll
  for (int q = 0; q < 16; ++q)
    *(float4*)&S[sbase + 4 * q] =
        make_float4(s[4 * q], s[4 * q + 1], s[4 * q + 2], s[4 * q + 3]);
  A_chunk[(size_t)(b * NCHUNK + chunk) * INNER + c] = p;
}

// ---------------------------------------------------------------- scan phase 2 (cross-chunk combine, in place)
__global__ __launch_bounds__(256) void scan_combine_kernel(
    float* __restrict__ S, const float* __restrict__ A_chunk) {
  const int idx = blockIdx.x * 256 + threadIdx.x;  // BATCH*INNER*NSTATE
  const int n = idx & 63;
  const int c = (idx >> 6) & (INNER - 1);
  const int b = idx >> 17;
  float s = 0.f;
  for (int k = 0; k < NCHUNK; ++k) {
    const size_t cs = (size_t)(b * NCHUNK + k) * INNER + c;
    const size_t off = cs * NSTATE + n;
    const float loc = S[off];
    S[off] = s;
    s = fmaf(A_chunk[cs], s, loc);
  }
}

// ---------------------------------------------------------------- scan phase 3 (full scan from prefix + skip + gate)
__global__ __launch_bounds__(256) void scan_out_kernel(
    const float* __restrict__ dtb, const __hip_bfloat16* __restrict__ xch,
    const float* __restrict__ Bm, const float* __restrict__ Cm,
    const float* __restrict__ S_in, const __hip_bfloat16* __restrict__ zbf,
    const float* __restrict__ Dv, __hip_bfloat16* __restrict__ ygated) {
  __shared__ float Bsh[TCHUNK][64];
  __shared__ float Csh[TCHUNK][64];
  const int b = blockIdx.z, chunk = blockIdx.y;
  const int c = blockIdx.x * 256 + threadIdx.x;
  const int t0 = chunk * TCHUNK;
  for (int i = threadIdx.x; i < TCHUNK * 16; i += 256) {
    const int row = i >> 4, q = i & 15;
    const size_t src = ((size_t)(b * SEQ + t0 + row)) * NSTATE + q * 4;
    *(float4*)&Bsh[row][q * 4] = *(const float4*)&Bm[src];
    *(float4*)&Csh[row][q * 4] = *(const float4*)&Cm[src];
  }
  __syncthreads();
  float s[64];
  const size_t sbase = ((size_t)(b * NCHUNK + chunk) * INNER + c) * NSTATE;
#pragma unroll
  for (int q = 0; q < 16; ++q) {
    const float4 v = *(const float4*)&S_in[sbase + 4 * q];
    s[4 * q] = v.x; s[4 * q + 1] = v.y; s[4 * q + 2] = v.z; s[4 * q + 3] = v.w;
  }
  const float Dc = Dv[c];
  const size_t base = (size_t)(b * SEQ + t0) * INNER + c;
  for (int t = 0; t < TCHUNK; ++t) {
    const float dtv = dtb[base + (size_t)t * INNER];
    const float at = __expf(-dtv);
    const float xc = __bfloat162float(xch[base + (size_t)t * INNER]);
    const float ut = dtv * xc;
    float y0 = 0.f, y1 = 0.f, y2 = 0.f, y3 = 0.f;
#pragma unroll
    for (int q = 0; q < 16; ++q) {
      const float4 bv = *(const float4*)&Bsh[t][q * 4];
      const float4 cv = *(const float4*)&Csh[t][q * 4];
      s[4 * q + 0] = fmaf(at, s[4 * q + 0], ut * bv.x);
      s[4 * q + 1] = fmaf(at, s[4 * q + 1], ut * bv.y);
      s[4 * q + 2] = fmaf(at, s[4 * q + 2], ut * bv.z);
      s[4 * q + 3] = fmaf(at, s[4 * q + 3], ut * bv.w);
      y0 = fmaf(s[4 * q + 0], cv.x, y0);
      y1 = fmaf(s[4 * q + 1], cv.y, y1);
      y2 = fmaf(s[4 * q + 2], cv.z, y2);
      y3 = fmaf(s[4 * q + 3], cv.w, y3);
    }
    const float yt = fmaf(Dc, xc, (y0 + y1) + (y2 + y3));
    const float z = __bfloat162float(zbf[base + (size_t)t * INNER]);
    const float g = z / (1.f + __expf(-z));
    ygated[base + (size_t)t * INNER] = __float2bfloat16(yt * g);
  }
}

// ---------------------------------------------------------------- launch
extern "C" void kernel_launch(void* const* d_in, const int* in_sizes, int n_in,
                              void* d_out, int out_size, void* d_ws, size_t ws_size,
                              hipStream_t stream) {
  const float* x      = (const float*)d_in[0];
  const float* W_in   = (const float*)d_in[1];
  const float* conv_w = (const float*)d_in[2];
  const float* conv_b = (const float*)d_in[3];
  const float* W_dt   = (const float*)d_in[4];
  const float* b_dt   = (const float*)d_in[5];
  const float* W_B    = (const float*)d_in[6];
  const float* W_C    = (const float*)d_in[7];
  const float* Dvec   = (const float*)d_in[8];
  const float* W_out  = (const float*)d_in[9];
  float* out = (float*)d_out;

  // ---- workspace layout with lifetime-based aliasing (~128 MiB) ----
  char* p = (char*)d_ws;
  auto alloc = [&](size_t bytes) {
    char* r = p;
    p += (bytes + 255) & ~(size_t)255;
    return r;
  };
  __hip_bfloat16* xin   = (__hip_bfloat16*)alloc((size_t)NTOK * INNER * 2);  // GEMM1 out; later ygated
  __hip_bfloat16* zbf   = (__hip_bfloat16*)alloc((size_t)NTOK * INNER * 2);
  char*           scr   = alloc((size_t)NTOK * INNER * 2);                   // x_bf+WinT; later xch
  __hip_bfloat16* WmidT = (__hip_bfloat16*)alloc((size_t)2304 * INNER * 2);  // padded to 2304 rows
  __hip_bfloat16* WoutT = (__hip_bfloat16*)alloc((size_t)HID * INNER * 2);
  float*          dtb   = (float*)alloc((size_t)NTOK * INNER * 4);
  float*          Bm    = (float*)alloc((size_t)NTOK * NSTATE * 4);
  float*          Cm    = (float*)alloc((size_t)NTOK * NSTATE * 4);
  float*          S     = (float*)alloc((size_t)BATCH * NCHUNK * INNER * NSTATE * 4);
  float*          A_chk = (float*)alloc((size_t)BATCH * NCHUNK * INNER * 4);

  __hip_bfloat16* x_bf   = (__hip_bfloat16*)scr;                              // 8 MB
  __hip_bfloat16* WinT   = (__hip_bfloat16*)(scr + (size_t)NTOK * HID * 2);   // 8 MB
  __hip_bfloat16* xch    = (__hip_bfloat16*)scr;                              // 16 MB (after GEMM1)
  __hip_bfloat16* ygated = xin;                                               // 16 MB (after conv)

  // 1. conversions / transposes
  cvt_f32_bf16_kernel<<<(NTOK * HID / 4 + 255) / 256, 256, 0, stream>>>(x, x_bf, NTOK * HID / 4);
  transpose_cvt_kernel<<<dim3((2 * INNER) / 32, HID / 32), 256, 0, stream>>>(W_in, WinT, HID, 2 * INNER, HID);
  transpose_cvt_kernel<<<dim3(INNER / 32, INNER / 32), 256, 0, stream>>>(W_dt, WmidT, INNER, INNER, INNER);
  transpose_cvt_kernel<<<dim3(NSTATE / 32, INNER / 32), 256, 0, stream>>>(
      W_B, WmidT + (size_t)INNER * INNER, INNER, NSTATE, INNER);
  transpose_cvt_kernel<<<dim3(NSTATE / 32, INNER / 32), 256, 0, stream>>>(
      W_C, WmidT + (size_t)(INNER + NSTATE) * INNER, INNER, NSTATE, INNER);
  transpose_cvt_kernel<<<dim3(HID / 32, INNER / 32), 256, 0, stream>>>(W_out, WoutT, INNER, HID, INNER);

  // 2. xz = x @ W_in  -> split bf16 (xin | z)   [M=4096, N=4096, K=1024]
  {
    const int gridN = (2 * INNER) / 256, nwg = (NTOK / 256) * gridN;  // 16x16=256
    gemm8p_kernel<1><<<nwg, 512, 0, stream>>>(
        x_bf, WinT, NTOK, 2 * INNER, HID, gridN, nwg, nullptr, 0,
        nullptr, xin, zbf, nullptr, nullptr, nullptr);
  }

  // 3. conv + silu  (xin -> xch; overwrites x_bf/WinT region)
  conv_silu_kernel<<<(NTOK * (INNER / 4)) / 256, 256, 0, stream>>>(xin, conv_w, conv_b, xch);

  // 4. mid GEMM (dt|B|C), N padded 2176->2304, fused softplus epilogue
  {
    const int gridN = 2304 / 256, nwg = (NTOK / 256) * gridN;  // 16x9=144
    gemm8p_kernel<2><<<nwg, 512, 0, stream>>>(
        xch, WmidT, NTOK, INNER + 2 * NSTATE, INNER, gridN, nwg, nullptr, 0,
        b_dt, nullptr, nullptr, dtb, Bm, Cm);
  }

  // 5. chunked selective scan
  scan_state_kernel<<<dim3(INNER / 256, NCHUNK, BATCH), 256, 0, stream>>>(dtb, xch, Bm, S, A_chk);
  scan_combine_kernel<<<(BATCH * INNER * NSTATE) / 256, 256, 0, stream>>>(S, A_chk);
  scan_out_kernel<<<dim3(INNER / 256, NCHUNK, BATCH), 256, 0, stream>>>(
      dtb, xch, Bm, Cm, S, zbf, Dvec, ygated);

  // 6. out = ygated @ W_out  [M=4096, N=1024, K=2048]
  {
    const int gridN = HID / 256, nwg = (NTOK / 256) * gridN;  // 16x4=64
    gemm8p_kernel<0><<<nwg, 512, 0, stream>>>(
        ygated, WoutT, NTOK, HID, INNER, gridN, nwg, out, HID,
        nullptr, nullptr, nullptr, nullptr, nullptr, nullptr);
  }
}

// Round 8
// 408.661 us; speedup vs baseline: 1.3813x; 1.3813x over previous
//
#include <hip/hip_runtime.h>
#include <hip/hip_bf16.h>
#include <math.h>

#define BATCH  2
#define SEQ    2048
#define HID    1024
#define INNER  2048
#define NSTATE 64
#define NTOK   (BATCH * SEQ)
#define TCHUNK 64
#define NCHUNK (SEQ / TCHUNK)

typedef __bf16 bf16x8 __attribute__((ext_vector_type(8)));
typedef float  f32x4  __attribute__((ext_vector_type(4)));

typedef const __attribute__((address_space(1))) char* gas_ptr;
typedef __attribute__((address_space(3))) char*       las_ptr;

__device__ __forceinline__ void gload16(const void* g, void* l) {
  __builtin_amdgcn_global_load_lds((gas_ptr)g, (las_ptr)l, 16, 0, 0);
}

__device__ __forceinline__ unsigned short f2bf(float f) {
  __hip_bfloat16 h = __float2bfloat16(f);
  return __builtin_bit_cast(unsigned short, h);
}
__device__ __forceinline__ float bf2f(unsigned short u) {
  unsigned int x = ((unsigned int)u) << 16;
  return __builtin_bit_cast(float, x);
}

// ---------------------------------------------------------------- cvt fp32->bf16
__global__ __launch_bounds__(256) void cvt_f32_bf16_kernel(
    const float* __restrict__ in, __hip_bfloat16* __restrict__ out, int n4) {
  int i = blockIdx.x * 256 + threadIdx.x;
  if (i >= n4) return;
  float4 v = ((const float4*)in)[i];
  ushort4 u;
  u.x = f2bf(v.x); u.y = f2bf(v.y); u.z = f2bf(v.z); u.w = f2bf(v.w);
  ((ushort4*)out)[i] = u;
}

// ------------------------------------------------- transpose fp32 [R][C] -> bf16 [C][ostride]
__global__ __launch_bounds__(256) void transpose_cvt_kernel(
    const float* __restrict__ in, __hip_bfloat16* __restrict__ out,
    int R, int C, int ostride) {
  __shared__ float tile[32][33];
  int tx = threadIdx.x & 31, ty = threadIdx.x >> 5;
  int c0 = blockIdx.x * 32, r0 = blockIdx.y * 32;
#pragma unroll
  for (int i = 0; i < 4; ++i)
    tile[ty + 8 * i][tx] = in[(size_t)(r0 + ty + 8 * i) * C + c0 + tx];
  __syncthreads();
#pragma unroll
  for (int i = 0; i < 4; ++i)
    out[(size_t)(c0 + ty + 8 * i) * ostride + r0 + tx] =
        __float2bfloat16(tile[tx][ty + 8 * i]);
}

// ---------------------------------------------------------------- GEMM: A[M,K] x Bt[N,K] -> C
// BK=64, single-buffered 32KB LDS, G4 XOR-swizzle (col16 ^= row&7) with linear
// gload_lds dest + inverse-permuted global source. Optional split-K (mnwg blocks/part).
// EPI 0: fp32 -> Cout (+ kz*M*ldc for split-K partials).
// EPI 1: bf16 split xin|z.  EPI 2: dt=softplus(v+bdt) | Bm | Cm.
template <int EPI>
__global__ __launch_bounds__(256, 4) void gemm_bt_kernel(
    const __hip_bfloat16* __restrict__ A, const __hip_bfloat16* __restrict__ Bt,
    int M, int N, int Klen, int ldk, int gridN, int nwg, int mnwg,
    float* __restrict__ Cout, int ldc,
    const float* __restrict__ bdt,
    __hip_bfloat16* __restrict__ o0, __hip_bfloat16* __restrict__ o1,
    float* __restrict__ f0, float* __restrict__ f1, float* __restrict__ f2) {
  __shared__ __align__(16) __hip_bfloat16 As[128 * 64];
  __shared__ __align__(16) __hip_bfloat16 Bs[128 * 64];
  const int tid = threadIdx.x;
  const int lane = tid & 63;
  const int w = tid >> 6;
  const int wr = w >> 1, wc = w & 1;

  // bijective XCD swizzle (m204)
  const int orig = blockIdx.x;
  const int q8 = nwg >> 3, r8 = nwg & 7;
  const int xcd = orig & 7, seq = orig >> 3;
  const int wg = (xcd < r8 ? xcd * (q8 + 1) : r8 * (q8 + 1) + (xcd - r8) * q8) + seq;
  const int kz = wg / mnwg;
  const int wgr = wg - kz * mnwg;
  const int m0 = (wgr / gridN) * 128;
  const int n0 = (wgr % gridN) * 128;

  const __hip_bfloat16* Ab = A + (size_t)kz * Klen;
  const __hip_bfloat16* Bb = Bt + (size_t)kz * Klen;

  f32x4 acc[4][4];
#pragma unroll
  for (int i = 0; i < 4; ++i)
#pragma unroll
    for (int j = 0; j < 4; ++j)
#pragma unroll
      for (int r2 = 0; r2 < 4; ++r2) acc[i][j][r2] = 0.f;

  // staging: wave w stages rows [w*32, w*32+32). Each gload16 covers 8 rows
  // (64 lanes x 16B; lane -> row w*32+g*8+(lane>>3), col16 lane&7).
  // Source col is pre-swizzled: col16s = (lane&7) ^ (lane>>3); LDS dest linear.
  const int g8row = lane >> 3;
  const int scol = ((lane & 7) ^ g8row) * 8;  // elements
  const __hip_bfloat16* Agp = Ab + (size_t)(m0 + w * 32 + g8row) * ldk + scol;
  const __hip_bfloat16* Bgp = Bb + (size_t)(n0 + w * 32 + g8row) * ldk + scol;
  __hip_bfloat16* lA = As + (w * 32) * 64;  // wave-uniform dests (+g*8 rows each)
  __hip_bfloat16* lB = Bs + (w * 32) * 64;

  const int lrow = lane & 15, lk = lane >> 4;
  const int arow0 = wr * 64 + lrow;   // + i*16
  const int brow0 = wc * 64 + lrow;   // + j*16

  const int nt = Klen >> 6;
  for (int t = 0; t < nt; ++t) {
    __syncthreads();  // previous tile's readers done
#pragma unroll
    for (int g = 0; g < 4; ++g) {
      gload16(Agp + (size_t)(g * 8) * ldk + t * 64, lA + (g * 8) * 64);
      gload16(Bgp + (size_t)(g * 8) * ldk + t * 64, lB + (g * 8) * 64);
    }
    __syncthreads();  // drains vmcnt(0): tile visible to all waves
#pragma unroll
    for (int ss = 0; ss < 2; ++ss) {
      bf16x8 af[4], bv[4];
#pragma unroll
      for (int i = 0; i < 4; ++i) {
        const int ra = arow0 + i * 16;
        af[i] = *(const bf16x8*)(As + ra * 64 + (((ss * 4 + lk) ^ (ra & 7)) * 8));
        const int rb = brow0 + i * 16;
        bv[i] = *(const bf16x8*)(Bs + rb * 64 + (((ss * 4 + lk) ^ (rb & 7)) * 8));
      }
#pragma unroll
      for (int i = 0; i < 4; ++i)
#pragma unroll
        for (int j = 0; j < 4; ++j)
          acc[i][j] = __builtin_amdgcn_mfma_f32_16x16x32_bf16(af[i], bv[j], acc[i][j], 0, 0, 0);
    }
  }

#pragma unroll
  for (int i = 0; i < 4; ++i) {
#pragma unroll
    for (int j = 0; j < 4; ++j) {
#pragma unroll
      for (int r2 = 0; r2 < 4; ++r2) {
        const int row = m0 + wr * 64 + i * 16 + lk * 4 + r2;
        const int col = n0 + wc * 64 + j * 16 + lrow;
        const float v = acc[i][j][r2];
        if constexpr (EPI == 0) {
          Cout[(size_t)kz * M * ldc + (size_t)row * ldc + col] = v;
        } else if constexpr (EPI == 1) {
          if (col < INNER) o0[(size_t)row * INNER + col] = __float2bfloat16(v);
          else             o1[(size_t)row * INNER + (col - INNER)] = __float2bfloat16(v);
        } else {
          if (col < INNER) {
            const float vv = v + bdt[col];
            const float dt = (vv > 15.f) ? vv : log1pf(expf(vv));
            f0[(size_t)row * INNER + col] = dt;
          } else {
            const int jn = col - INNER;
            if (jn < NSTATE) f1[(size_t)row * NSTATE + jn] = v;
            else             f2[(size_t)row * NSTATE + (jn - NSTATE)] = v;
          }
        }
      }
    }
  }
}

// ---------------------------------------------------------------- split-K reduce: out = P0 + P1 (fp32)
__global__ __launch_bounds__(256) void reduce2_kernel(
    const float* __restrict__ P, float* __restrict__ out, int n4) {
  int i = blockIdx.x * 256 + threadIdx.x;
  if (i >= n4) return;
  float4 a = ((const float4*)P)[i];
  float4 b = ((const float4*)P)[i + n4];
  ((float4*)out)[i] = make_float4(a.x + b.x, a.y + b.y, a.z + b.z, a.w + b.w);
}

// ---------------------------------------------------------------- causal depthwise conv + silu (bf16 in, bf16 out)
__global__ __launch_bounds__(256) void conv_silu_kernel(
    const __hip_bfloat16* __restrict__ xin, const float* __restrict__ cw,
    const float* __restrict__ cb, __hip_bfloat16* __restrict__ xch) {
  int idx = blockIdx.x * 256 + threadIdx.x;  // NTOK * (INNER/4)
  int cg = idx & 511;
  int tok = idx >> 9;
  int c = cg * 4;
  int l = tok & (SEQ - 1);
  float wv[4][4];
#pragma unroll
  for (int i = 0; i < 4; ++i) {
    float4 w = *(const float4*)&cw[(c + i) * 4];
    wv[i][0] = w.x; wv[i][1] = w.y; wv[i][2] = w.z; wv[i][3] = w.w;
  }
  float4 bias = *(const float4*)&cb[c];
  float r0 = bias.x, r1 = bias.y, r2 = bias.z, r3 = bias.w;
#pragma unroll
  for (int k = 0; k < 4; ++k) {
    const int d = 3 - k;
    if (l >= d) {
      ushort4 xv = *(const ushort4*)&xin[(size_t)(tok - d) * INNER + c];
      r0 = fmaf(bf2f(xv.x), wv[0][k], r0);
      r1 = fmaf(bf2f(xv.y), wv[1][k], r1);
      r2 = fmaf(bf2f(xv.z), wv[2][k], r2);
      r3 = fmaf(bf2f(xv.w), wv[3][k], r3);
    }
  }
  r0 = r0 / (1.f + __expf(-r0));
  r1 = r1 / (1.f + __expf(-r1));
  r2 = r2 / (1.f + __expf(-r2));
  r3 = r3 / (1.f + __expf(-r3));
  ushort4 u;
  u.x = f2bf(r0); u.y = f2bf(r1); u.z = f2bf(r2); u.w = f2bf(r3);
  *(ushort4*)&xch[(size_t)tok * INNER + c] = u;
}

// ---------------------------------------------------------------- scan phase 1 (within-chunk states only)
__global__ __launch_bounds__(256) void scan_state_kernel(
    const float* __restrict__ dtb, const __hip_bfloat16* __restrict__ xch,
    const float* __restrict__ Bm,
    float* __restrict__ S, float* __restrict__ A_chunk) {
  __shared__ float Bsh[TCHUNK][64];
  const int b = blockIdx.z, chunk = blockIdx.y;
  const int c = blockIdx.x * 256 + threadIdx.x;
  const int t0 = chunk * TCHUNK;
  for (int i = threadIdx.x; i < TCHUNK * 16; i += 256) {
    const int row = i >> 4, q = i & 15;
    *(float4*)&Bsh[row][q * 4] =
        *(const float4*)&Bm[((size_t)(b * SEQ + t0 + row)) * NSTATE + q * 4];
  }
  __syncthreads();
  float s[64];
#pragma unroll
  for (int n = 0; n < 64; ++n) s[n] = 0.f;
  float p = 1.f;
  const size_t base = (size_t)(b * SEQ + t0) * INNER + c;
  for (int t = 0; t < TCHUNK; ++t) {
    const float dtv = dtb[base + (size_t)t * INNER];
    const float at = __expf(-dtv);
    const float xc = __bfloat162float(xch[base + (size_t)t * INNER]);
    const float ut = dtv * xc;
    p *= at;
#pragma unroll
    for (int q = 0; q < 16; ++q) {
      const float4 bv = *(const float4*)&Bsh[t][q * 4];
      s[4 * q + 0] = fmaf(at, s[4 * q + 0], ut * bv.x);
      s[4 * q + 1] = fmaf(at, s[4 * q + 1], ut * bv.y);
      s[4 * q + 2] = fmaf(at, s[4 * q + 2], ut * bv.z);
      s[4 * q + 3] = fmaf(at, s[4 * q + 3], ut * bv.w);
    }
  }
  const size_t sbase = ((size_t)(b * NCHUNK + chunk) * INNER + c) * NSTATE;
#pragma unroll
  for (int q = 0; q < 16; ++q)
    *(float4*)&S[sbase + 4 * q] =
        make_float4(s[4 * q], s[4 * q + 1], s[4 * q + 2], s[4 * q + 3]);
  A_chunk[(size_t)(b * NCHUNK + chunk) * INNER + c] = p;
}

// ---------------------------------------------------------------- scan phase 2 (cross-chunk combine, in place)
__global__ __launch_bounds__(256) void scan_combine_kernel(
    float* __restrict__ S, const float* __restrict__ A_chunk) {
  const int idx = blockIdx.x * 256 + threadIdx.x;  // BATCH*INNER*NSTATE
  const int n = idx & 63;
  const int c = (idx >> 6) & (INNER - 1);
  const int b = idx >> 17;
  float s = 0.f;
  for (int k = 0; k < NCHUNK; ++k) {
    const size_t cs = (size_t)(b * NCHUNK + k) * INNER + c;
    const size_t off = cs * NSTATE + n;
    const float loc = S[off];
    S[off] = s;
    s = fmaf(A_chunk[cs], s, loc);
  }
}

// ---------------------------------------------------------------- scan phase 3 (full scan from prefix + skip + gate)
__global__ __launch_bounds__(256) void scan_out_kernel(
    const float* __restrict__ dtb, const __hip_bfloat16* __restrict__ xch,
    const float* __restrict__ Bm, const float* __restrict__ Cm,
    const float* __restrict__ S_in, const __hip_bfloat16* __restrict__ zbf,
    const float* __restrict__ Dv, __hip_bfloat16* __restrict__ ygated) {
  __shared__ float Bsh[TCHUNK][64];
  __shared__ float Csh[TCHUNK][64];
  const int b = blockIdx.z, chunk = blockIdx.y;
  const int c = blockIdx.x * 256 + threadIdx.x;
  const int t0 = chunk * TCHUNK;
  for (int i = threadIdx.x; i < TCHUNK * 16; i += 256) {
    const int row = i >> 4, q = i & 15;
    const size_t src = ((size_t)(b * SEQ + t0 + row)) * NSTATE + q * 4;
    *(float4*)&Bsh[row][q * 4] = *(const float4*)&Bm[src];
    *(float4*)&Csh[row][q * 4] = *(const float4*)&Cm[src];
  }
  __syncthreads();
  float s[64];
  const size_t sbase = ((size_t)(b * NCHUNK + chunk) * INNER + c) * NSTATE;
#pragma unroll
  for (int q = 0; q < 16; ++q) {
    const float4 v = *(const float4*)&S_in[sbase + 4 * q];
    s[4 * q] = v.x; s[4 * q + 1] = v.y; s[4 * q + 2] = v.z; s[4 * q + 3] = v.w;
  }
  const float Dc = Dv[c];
  const size_t base = (size_t)(b * SEQ + t0) * INNER + c;
  for (int t = 0; t < TCHUNK; ++t) {
    const float dtv = dtb[base + (size_t)t * INNER];
    const float at = __expf(-dtv);
    const float xc = __bfloat162float(xch[base + (size_t)t * INNER]);
    const float ut = dtv * xc;
    float y0 = 0.f, y1 = 0.f, y2 = 0.f, y3 = 0.f;
#pragma unroll
    for (int q = 0; q < 16; ++q) {
      const float4 bv = *(const float4*)&Bsh[t][q * 4];
      const float4 cv = *(const float4*)&Csh[t][q * 4];
      s[4 * q + 0] = fmaf(at, s[4 * q + 0], ut * bv.x);
      s[4 * q + 1] = fmaf(at, s[4 * q + 1], ut * bv.y);
      s[4 * q + 2] = fmaf(at, s[4 * q + 2], ut * bv.z);
      s[4 * q + 3] = fmaf(at, s[4 * q + 3], ut * bv.w);
      y0 = fmaf(s[4 * q + 0], cv.x, y0);
      y1 = fmaf(s[4 * q + 1], cv.y, y1);
      y2 = fmaf(s[4 * q + 2], cv.z, y2);
      y3 = fmaf(s[4 * q + 3], cv.w, y3);
    }
    const float yt = fmaf(Dc, xc, (y0 + y1) + (y2 + y3));
    const float z = __bfloat162float(zbf[base + (size_t)t * INNER]);
    const float g = z / (1.f + __expf(-z));
    ygated[base + (size_t)t * INNER] = __float2bfloat16(yt * g);
  }
}

// ---------------------------------------------------------------- launch
extern "C" void kernel_launch(void* const* d_in, const int* in_sizes, int n_in,
                              void* d_out, int out_size, void* d_ws, size_t ws_size,
                              hipStream_t stream) {
  const float* x      = (const float*)d_in[0];
  const float* W_in   = (const float*)d_in[1];
  const float* conv_w = (const float*)d_in[2];
  const float* conv_b = (const float*)d_in[3];
  const float* W_dt   = (const float*)d_in[4];
  const float* b_dt   = (const float*)d_in[5];
  const float* W_B    = (const float*)d_in[6];
  const float* W_C    = (const float*)d_in[7];
  const float* Dvec   = (const float*)d_in[8];
  const float* W_out  = (const float*)d_in[9];
  float* out = (float*)d_out;

  // ---- workspace layout with lifetime-based aliasing (~127 MiB) ----
  char* p = (char*)d_ws;
  auto alloc = [&](size_t bytes) {
    char* r = p;
    p += (bytes + 255) & ~(size_t)255;
    return r;
  };
  __hip_bfloat16* xin   = (__hip_bfloat16*)alloc((size_t)NTOK * INNER * 2);  // GEMM1 out; later ygated
  __hip_bfloat16* zbf   = (__hip_bfloat16*)alloc((size_t)NTOK * INNER * 2);
  char*           scr   = alloc((size_t)NTOK * INNER * 2);                   // x_bf+WinT; later xch
  __hip_bfloat16* WmidT = (__hip_bfloat16*)alloc((size_t)(INNER + 2 * NSTATE) * INNER * 2);
  __hip_bfloat16* WoutT = (__hip_bfloat16*)alloc((size_t)HID * INNER * 2);
  float*          dtb   = (float*)alloc((size_t)NTOK * INNER * 4);
  float*          Bm    = (float*)alloc((size_t)NTOK * NSTATE * 4);
  float*          Cm    = (float*)alloc((size_t)NTOK * NSTATE * 4);
  float*          S     = (float*)alloc((size_t)BATCH * NCHUNK * INNER * NSTATE * 4);  // 64MB
  float*          A_chk = (float*)alloc((size_t)BATCH * NCHUNK * INNER * 4);

  __hip_bfloat16* x_bf   = (__hip_bfloat16*)scr;                              // 8 MB
  __hip_bfloat16* WinT   = (__hip_bfloat16*)(scr + (size_t)NTOK * HID * 2);   // 8 MB
  __hip_bfloat16* xch    = (__hip_bfloat16*)scr;                              // 16 MB (after GEMM1)
  __hip_bfloat16* ygated = xin;                                               // 16 MB (after conv)
  float*          Pbuf   = S;  // split-K partials (32 MB), S dead after scan_out

  // 1. conversions / transposes
  cvt_f32_bf16_kernel<<<(NTOK * HID / 4 + 255) / 256, 256, 0, stream>>>(x, x_bf, NTOK * HID / 4);
  transpose_cvt_kernel<<<dim3((2 * INNER) / 32, HID / 32), 256, 0, stream>>>(W_in, WinT, HID, 2 * INNER, HID);
  transpose_cvt_kernel<<<dim3(INNER / 32, INNER / 32), 256, 0, stream>>>(W_dt, WmidT, INNER, INNER, INNER);
  transpose_cvt_kernel<<<dim3(NSTATE / 32, INNER / 32), 256, 0, stream>>>(
      W_B, WmidT + (size_t)INNER * INNER, INNER, NSTATE, INNER);
  transpose_cvt_kernel<<<dim3(NSTATE / 32, INNER / 32), 256, 0, stream>>>(
      W_C, WmidT + (size_t)(INNER + NSTATE) * INNER, INNER, NSTATE, INNER);
  transpose_cvt_kernel<<<dim3(HID / 32, INNER / 32), 256, 0, stream>>>(W_out, WoutT, INNER, HID, INNER);

  // 2. xz = x @ W_in  -> split bf16 (xin | z)   [M=4096, N=4096, K=1024]
  {
    const int gridN = (2 * INNER) / 128, nwg = (NTOK / 128) * gridN;  // 1024
    gemm_bt_kernel<1><<<nwg, 256, 0, stream>>>(
        x_bf, WinT, NTOK, 2 * INNER, HID, HID, gridN, nwg, nwg, nullptr, 0,
        nullptr, xin, zbf, nullptr, nullptr, nullptr);
  }

  // 3. conv + silu  (xin -> xch; overwrites x_bf/WinT region)
  conv_silu_kernel<<<(NTOK * (INNER / 4)) / 256, 256, 0, stream>>>(xin, conv_w, conv_b, xch);

  // 4. mid GEMM (dt|B|C), fused softplus epilogue  [M=4096, N=2176, K=2048]
  {
    const int gridN = (INNER + 2 * NSTATE) / 128, nwg = (NTOK / 128) * gridN;  // 544
    gemm_bt_kernel<2><<<nwg, 256, 0, stream>>>(
        xch, WmidT, NTOK, INNER + 2 * NSTATE, INNER, INNER, gridN, nwg, nwg, nullptr, 0,
        b_dt, nullptr, nullptr, dtb, Bm, Cm);
  }

  // 5. chunked selective scan
  scan_state_kernel<<<dim3(INNER / 256, NCHUNK, BATCH), 256, 0, stream>>>(dtb, xch, Bm, S, A_chk);
  scan_combine_kernel<<<(BATCH * INNER * NSTATE) / 256, 256, 0, stream>>>(S, A_chk);
  scan_out_kernel<<<dim3(INNER / 256, NCHUNK, BATCH), 256, 0, stream>>>(
      dtb, xch, Bm, Cm, S, zbf, Dvec, ygated);

  // 6. out = ygated @ W_out  [M=4096, N=1024, K=2048], split-K x2 + reduce
  {
    const int gridN = HID / 128;                     // 8
    const int mnwg = (NTOK / 128) * gridN;           // 256 blocks per K-part
    const int nwg = mnwg * 2;                        // 512
    gemm_bt_kernel<0><<<nwg, 256, 0, stream>>>(
        ygated, WoutT, NTOK, HID, INNER / 2, INNER, gridN, nwg, mnwg, Pbuf, HID,
        nullptr, nullptr, nullptr, nullptr, nullptr, nullptr);
    const int n4 = NTOK * HID / 4;
    reduce2_kernel<<<(n4 + 255) / 256, 256, 0, stream>>>(Pbuf, out, n4);
  }
}

// Round 9
// 389.149 us; speedup vs baseline: 1.4505x; 1.0501x over previous
//
#include <hip/hip_runtime.h>
#include <hip/hip_bf16.h>
#include <math.h>

#define BATCH  2
#define SEQ    2048
#define HID    1024
#define INNER  2048
#define NSTATE 64
#define NTOK   (BATCH * SEQ)
#define TCHUNK 64
#define NCHUNK (SEQ / TCHUNK)
#define NMID   (INNER + 2 * NSTATE)   // 2176

typedef __bf16 bf16x8 __attribute__((ext_vector_type(8)));
typedef float  f32x4  __attribute__((ext_vector_type(4)));

typedef const __attribute__((address_space(1))) char* gas_ptr;
typedef __attribute__((address_space(3))) char*       las_ptr;

__device__ __forceinline__ void gload16(const void* g, void* l) {
  __builtin_amdgcn_global_load_lds((gas_ptr)g, (las_ptr)l, 16, 0, 0);
}

__device__ __forceinline__ unsigned short f2bf(float f) {
  __hip_bfloat16 h = __float2bfloat16(f);
  return __builtin_bit_cast(unsigned short, h);
}
__device__ __forceinline__ float bf2f(unsigned short u) {
  unsigned int x = ((unsigned int)u) << 16;
  return __builtin_bit_cast(float, x);
}

// ---------------------------------------------------------------- cvt fp32->bf16
__global__ __launch_bounds__(256) void cvt_f32_bf16_kernel(
    const float* __restrict__ in, __hip_bfloat16* __restrict__ out, int n4) {
  int i = blockIdx.x * 256 + threadIdx.x;
  if (i >= n4) return;
  float4 v = ((const float4*)in)[i];
  ushort4 u;
  u.x = f2bf(v.x); u.y = f2bf(v.y); u.z = f2bf(v.z); u.w = f2bf(v.w);
  ((ushort4*)out)[i] = u;
}

// ------------------------------------------------- transpose fp32 [R][C] -> bf16 [C][ostride]
__global__ __launch_bounds__(256) void transpose_cvt_kernel(
    const float* __restrict__ in, __hip_bfloat16* __restrict__ out,
    int R, int C, int ostride) {
  __shared__ float tile[32][33];
  int tx = threadIdx.x & 31, ty = threadIdx.x >> 5;
  int c0 = blockIdx.x * 32, r0 = blockIdx.y * 32;
#pragma unroll
  for (int i = 0; i < 4; ++i)
    tile[ty + 8 * i][tx] = in[(size_t)(r0 + ty + 8 * i) * C + c0 + tx];
  __syncthreads();
#pragma unroll
  for (int i = 0; i < 4; ++i)
    out[(size_t)(c0 + ty + 8 * i) * ostride + r0 + tx] =
        __float2bfloat16(tile[tx][ty + 8 * i]);
}

// ---------------------------------------------------------------- GEMM: A[M,K] x Bt[N,K] -> C
// BK=64, single-buffered 32KB LDS, G4 XOR-swizzle (conflict-free, verified r8).
// Split-K: Klen = K/parts, kz = wg / mnwg, partials at Cout + kz*M*ldc.
// EPI 0: fp32 -> Cout.  EPI 1: bf16 split xin|z.
template <int EPI>
__global__ __launch_bounds__(256, 4) void gemm_bt_kernel(
    const __hip_bfloat16* __restrict__ A, const __hip_bfloat16* __restrict__ Bt,
    int M, int N, int Klen, int ldk, int gridN, int nwg, int mnwg,
    float* __restrict__ Cout, int ldc,
    __hip_bfloat16* __restrict__ o0, __hip_bfloat16* __restrict__ o1) {
  __shared__ __align__(16) __hip_bfloat16 As[128 * 64];
  __shared__ __align__(16) __hip_bfloat16 Bs[128 * 64];
  const int tid = threadIdx.x;
  const int lane = tid & 63;
  const int w = tid >> 6;
  const int wr = w >> 1, wc = w & 1;

  // bijective XCD swizzle (m204)
  const int orig = blockIdx.x;
  const int q8 = nwg >> 3, r8 = nwg & 7;
  const int xcd = orig & 7, seq = orig >> 3;
  const int wg = (xcd < r8 ? xcd * (q8 + 1) : r8 * (q8 + 1) + (xcd - r8) * q8) + seq;
  const int kz = wg / mnwg;
  const int wgr = wg - kz * mnwg;
  const int m0 = (wgr / gridN) * 128;
  const int n0 = (wgr % gridN) * 128;

  const __hip_bfloat16* Ab = A + (size_t)kz * Klen;
  const __hip_bfloat16* Bb = Bt + (size_t)kz * Klen;

  f32x4 acc[4][4];
#pragma unroll
  for (int i = 0; i < 4; ++i)
#pragma unroll
    for (int j = 0; j < 4; ++j)
#pragma unroll
      for (int r2 = 0; r2 < 4; ++r2) acc[i][j][r2] = 0.f;

  // staging: wave w stages rows [w*32, w*32+32); 8 rows per gload16;
  // source col pre-swizzled (lane&7)^(lane>>3), LDS dest linear.
  const int g8row = lane >> 3;
  const int scol = ((lane & 7) ^ g8row) * 8;
  const __hip_bfloat16* Agp = Ab + (size_t)(m0 + w * 32 + g8row) * ldk + scol;
  const __hip_bfloat16* Bgp = Bb + (size_t)(n0 + w * 32 + g8row) * ldk + scol;
  __hip_bfloat16* lA = As + (w * 32) * 64;
  __hip_bfloat16* lB = Bs + (w * 32) * 64;

  const int lrow = lane & 15, lk = lane >> 4;
  const int arow0 = wr * 64 + lrow;
  const int brow0 = wc * 64 + lrow;

  const int nt = Klen >> 6;
  for (int t = 0; t < nt; ++t) {
    __syncthreads();
#pragma unroll
    for (int g = 0; g < 4; ++g) {
      gload16(Agp + (size_t)(g * 8) * ldk + t * 64, lA + (g * 8) * 64);
      gload16(Bgp + (size_t)(g * 8) * ldk + t * 64, lB + (g * 8) * 64);
    }
    __syncthreads();
#pragma unroll
    for (int ss = 0; ss < 2; ++ss) {
      bf16x8 af[4], bv[4];
#pragma unroll
      for (int i = 0; i < 4; ++i) {
        const int ra = arow0 + i * 16;
        af[i] = *(const bf16x8*)(As + ra * 64 + (((ss * 4 + lk) ^ (ra & 7)) * 8));
        const int rb = brow0 + i * 16;
        bv[i] = *(const bf16x8*)(Bs + rb * 64 + (((ss * 4 + lk) ^ (rb & 7)) * 8));
      }
#pragma unroll
      for (int i = 0; i < 4; ++i)
#pragma unroll
        for (int j = 0; j < 4; ++j)
          acc[i][j] = __builtin_amdgcn_mfma_f32_16x16x32_bf16(af[i], bv[j], acc[i][j], 0, 0, 0);
    }
  }

#pragma unroll
  for (int i = 0; i < 4; ++i) {
#pragma unroll
    for (int j = 0; j < 4; ++j) {
#pragma unroll
      for (int r2 = 0; r2 < 4; ++r2) {
        const int row = m0 + wr * 64 + i * 16 + lk * 4 + r2;
        const int col = n0 + wc * 64 + j * 16 + lrow;
        const float v = acc[i][j][r2];
        if constexpr (EPI == 0) {
          Cout[(size_t)kz * M * ldc + (size_t)row * ldc + col] = v;
        } else {
          if (col < INNER) o0[(size_t)row * INNER + col] = __float2bfloat16(v);
          else             o1[(size_t)row * INNER + (col - INNER)] = __float2bfloat16(v);
        }
      }
    }
  }
}

// ---------------------------------------------------------------- mid reduce: P0+P1 -> softplus/dt | Bm | Cm
__global__ __launch_bounds__(256) void reduce_mid_kernel(
    const float* __restrict__ P, const float* __restrict__ bdt,
    float* __restrict__ dtb, float* __restrict__ Bm, float* __restrict__ Cm) {
  const int i = blockIdx.x * 256 + threadIdx.x;     // NTOK * NMID / 4
  const int row = i / (NMID / 4);
  const int c4 = i - row * (NMID / 4);
  const int col = c4 * 4;
  const size_t off = (size_t)row * NMID + col;
  float4 a = *(const float4*)&P[off];
  float4 b = *(const float4*)&P[(size_t)NTOK * NMID + off];
  float4 v = make_float4(a.x + b.x, a.y + b.y, a.z + b.z, a.w + b.w);
  if (col < INNER) {
    float4 bb = *(const float4*)&bdt[col];
    float4 d;
    d.x = v.x + bb.x; d.y = v.y + bb.y; d.z = v.z + bb.z; d.w = v.w + bb.w;
    d.x = (d.x > 15.f) ? d.x : log1pf(__expf(d.x));
    d.y = (d.y > 15.f) ? d.y : log1pf(__expf(d.y));
    d.z = (d.z > 15.f) ? d.z : log1pf(__expf(d.z));
    d.w = (d.w > 15.f) ? d.w : log1pf(__expf(d.w));
    *(float4*)&dtb[(size_t)row * INNER + col] = d;
  } else if (col < INNER + NSTATE) {
    *(float4*)&Bm[(size_t)row * NSTATE + (col - INNER)] = v;
  } else {
    *(float4*)&Cm[(size_t)row * NSTATE + (col - INNER - NSTATE)] = v;
  }
}

// ---------------------------------------------------------------- split-K4 reduce (fp32)
__global__ __launch_bounds__(256) void reduce4_kernel(
    const float* __restrict__ P, float* __restrict__ out, int n4) {
  int i = blockIdx.x * 256 + threadIdx.x;
  if (i >= n4) return;
  float4 a = ((const float4*)P)[i];
  float4 b = ((const float4*)P)[i + n4];
  float4 c = ((const float4*)P)[i + 2 * n4];
  float4 d = ((const float4*)P)[i + 3 * n4];
  ((float4*)out)[i] = make_float4((a.x + b.x) + (c.x + d.x), (a.y + b.y) + (c.y + d.y),
                                  (a.z + b.z) + (c.z + d.z), (a.w + b.w) + (c.w + d.w));
}

// ---------------------------------------------------------------- causal depthwise conv + silu
__global__ __launch_bounds__(256) void conv_silu_kernel(
    const __hip_bfloat16* __restrict__ xin, const float* __restrict__ cw,
    const float* __restrict__ cb, __hip_bfloat16* __restrict__ xch) {
  int idx = blockIdx.x * 256 + threadIdx.x;
  int cg = idx & 511;
  int tok = idx >> 9;
  int c = cg * 4;
  int l = tok & (SEQ - 1);
  float wv[4][4];
#pragma unroll
  for (int i = 0; i < 4; ++i) {
    float4 w = *(const float4*)&cw[(c + i) * 4];
    wv[i][0] = w.x; wv[i][1] = w.y; wv[i][2] = w.z; wv[i][3] = w.w;
  }
  float4 bias = *(const float4*)&cb[c];
  float r0 = bias.x, r1 = bias.y, r2 = bias.z, r3 = bias.w;
#pragma unroll
  for (int k = 0; k < 4; ++k) {
    const int d = 3 - k;
    if (l >= d) {
      ushort4 xv = *(const ushort4*)&xin[(size_t)(tok - d) * INNER + c];
      r0 = fmaf(bf2f(xv.x), wv[0][k], r0);
      r1 = fmaf(bf2f(xv.y), wv[1][k], r1);
      r2 = fmaf(bf2f(xv.z), wv[2][k], r2);
      r3 = fmaf(bf2f(xv.w), wv[3][k], r3);
    }
  }
  r0 = r0 / (1.f + __expf(-r0));
  r1 = r1 / (1.f + __expf(-r1));
  r2 = r2 / (1.f + __expf(-r2));
  r3 = r3 / (1.f + __expf(-r3));
  ushort4 u;
  u.x = f2bf(r0); u.y = f2bf(r1); u.z = f2bf(r2); u.w = f2bf(r3);
  *(ushort4*)&xch[(size_t)tok * INNER + c] = u;
}

// ---------------------------------------------------------------- scan phase 1
__global__ __launch_bounds__(256) void scan_state_kernel(
    const float* __restrict__ dtb, const __hip_bfloat16* __restrict__ xch,
    const float* __restrict__ Bm,
    float* __restrict__ S, float* __restrict__ A_chunk) {
  __shared__ float Bsh[TCHUNK][64];
  const int b = blockIdx.z, chunk = blockIdx.y;
  const int c = blockIdx.x * 256 + threadIdx.x;
  const int t0 = chunk * TCHUNK;
  for (int i = threadIdx.x; i < TCHUNK * 16; i += 256) {
    const int row = i >> 4, q = i & 15;
    *(float4*)&Bsh[row][q * 4] =
        *(const float4*)&Bm[((size_t)(b * SEQ + t0 + row)) * NSTATE + q * 4];
  }
  __syncthreads();
  float s[64];
#pragma unroll
  for (int n = 0; n < 64; ++n) s[n] = 0.f;
  float p = 1.f;
  const size_t base = (size_t)(b * SEQ + t0) * INNER + c;
  for (int t = 0; t < TCHUNK; ++t) {
    const float dtv = dtb[base + (size_t)t * INNER];
    const float at = __expf(-dtv);
    const float xc = __bfloat162float(xch[base + (size_t)t * INNER]);
    const float ut = dtv * xc;
    p *= at;
#pragma unroll
    for (int q = 0; q < 16; ++q) {
      const float4 bv = *(const float4*)&Bsh[t][q * 4];
      s[4 * q + 0] = fmaf(at, s[4 * q + 0], ut * bv.x);
      s[4 * q + 1] = fmaf(at, s[4 * q + 1], ut * bv.y);
      s[4 * q + 2] = fmaf(at, s[4 * q + 2], ut * bv.z);
      s[4 * q + 3] = fmaf(at, s[4 * q + 3], ut * bv.w);
    }
  }
  const size_t sbase = ((size_t)(b * NCHUNK + chunk) * INNER + c) * NSTATE;
#pragma unroll
  for (int q = 0; q < 16; ++q)
    *(float4*)&S[sbase + 4 * q] =
        make_float4(s[4 * q], s[4 * q + 1], s[4 * q + 2], s[4 * q + 3]);
  A_chunk[(size_t)(b * NCHUNK + chunk) * INNER + c] = p;
}

// ---------------------------------------------------------------- scan phase 2 (in place)
__global__ __launch_bounds__(256) void scan_combine_kernel(
    float* __restrict__ S, const float* __restrict__ A_chunk) {
  const int idx = blockIdx.x * 256 + threadIdx.x;
  const int n = idx & 63;
  const int c = (idx >> 6) & (INNER - 1);
  const int b = idx >> 17;
  float s = 0.f;
  for (int k = 0; k < NCHUNK; ++k) {
    const size_t cs = (size_t)(b * NCHUNK + k) * INNER + c;
    const size_t off = cs * NSTATE + n;
    const float loc = S[off];
    S[off] = s;
    s = fmaf(A_chunk[cs], s, loc);
  }
}

// ---------------------------------------------------------------- scan phase 3
__global__ __launch_bounds__(256) void scan_out_kernel(
    const float* __restrict__ dtb, const __hip_bfloat16* __restrict__ xch,
    const float* __restrict__ Bm, const float* __restrict__ Cm,
    const float* __restrict__ S_in, const __hip_bfloat16* __restrict__ zbf,
    const float* __restrict__ Dv, __hip_bfloat16* __restrict__ ygated) {
  __shared__ float Bsh[TCHUNK][64];
  __shared__ float Csh[TCHUNK][64];
  const int b = blockIdx.z, chunk = blockIdx.y;
  const int c = blockIdx.x * 256 + threadIdx.x;
  const int t0 = chunk * TCHUNK;
  for (int i = threadIdx.x; i < TCHUNK * 16; i += 256) {
    const int row = i >> 4, q = i & 15;
    const size_t src = ((size_t)(b * SEQ + t0 + row)) * NSTATE + q * 4;
    *(float4*)&Bsh[row][q * 4] = *(const float4*)&Bm[src];
    *(float4*)&Csh[row][q * 4] = *(const float4*)&Cm[src];
  }
  __syncthreads();
  float s[64];
  const size_t sbase = ((size_t)(b * NCHUNK + chunk) * INNER + c) * NSTATE;
#pragma unroll
  for (int q = 0; q < 16; ++q) {
    const float4 v = *(const float4*)&S_in[sbase + 4 * q];
    s[4 * q] = v.x; s[4 * q + 1] = v.y; s[4 * q + 2] = v.z; s[4 * q + 3] = v.w;
  }
  const float Dc = Dv[c];
  const size_t base = (size_t)(b * SEQ + t0) * INNER + c;
  for (int t = 0; t < TCHUNK; ++t) {
    const float dtv = dtb[base + (size_t)t * INNER];
    const float at = __expf(-dtv);
    const float xc = __bfloat162float(xch[base + (size_t)t * INNER]);
    const float ut = dtv * xc;
    float y0 = 0.f, y1 = 0.f, y2 = 0.f, y3 = 0.f;
#pragma unroll
    for (int q = 0; q < 16; ++q) {
      const float4 bv = *(const float4*)&Bsh[t][q * 4];
      const float4 cv = *(const float4*)&Csh[t][q * 4];
      s[4 * q + 0] = fmaf(at, s[4 * q + 0], ut * bv.x);
      s[4 * q + 1] = fmaf(at, s[4 * q + 1], ut * bv.y);
      s[4 * q + 2] = fmaf(at, s[4 * q + 2], ut * bv.z);
      s[4 * q + 3] = fmaf(at, s[4 * q + 3], ut * bv.w);
      y0 = fmaf(s[4 * q + 0], cv.x, y0);
      y1 = fmaf(s[4 * q + 1], cv.y, y1);
      y2 = fmaf(s[4 * q + 2], cv.z, y2);
      y3 = fmaf(s[4 * q + 3], cv.w, y3);
    }
    const float yt = fmaf(Dc, xc, (y0 + y1) + (y2 + y3));
    const float z = __bfloat162float(zbf[base + (size_t)t * INNER]);
    const float g = z / (1.f + __expf(-z));
    ygated[base + (size_t)t * INNER] = __float2bfloat16(yt * g);
  }
}

// ---------------------------------------------------------------- launch
extern "C" void kernel_launch(void* const* d_in, const int* in_sizes, int n_in,
                              void* d_out, int out_size, void* d_ws, size_t ws_size,
                              hipStream_t stream) {
  const float* x      = (const float*)d_in[0];
  const float* W_in   = (const float*)d_in[1];
  const float* conv_w = (const float*)d_in[2];
  const float* conv_b = (const float*)d_in[3];
  const float* W_dt   = (const float*)d_in[4];
  const float* b_dt   = (const float*)d_in[5];
  const float* W_B    = (const float*)d_in[6];
  const float* W_C    = (const float*)d_in[7];
  const float* Dvec   = (const float*)d_in[8];
  const float* W_out  = (const float*)d_in[9];
  float* out = (float*)d_out;

  // ---- workspace layout (~234 MiB; round-0 proved ws >= 334 MB) ----
  char* p = (char*)d_ws;
  auto alloc = [&](size_t bytes) {
    char* r = p;
    p += (bytes + 255) & ~(size_t)255;
    return r;
  };
  __hip_bfloat16* xin   = (__hip_bfloat16*)alloc((size_t)NTOK * INNER * 2);  // later ygated
  __hip_bfloat16* zbf   = (__hip_bfloat16*)alloc((size_t)NTOK * INNER * 2);
  char*           scr   = alloc((size_t)NTOK * INNER * 2);                   // x_bf+WinT; later xch
  __hip_bfloat16* WmidT = (__hip_bfloat16*)alloc((size_t)NMID * INNER * 2);
  __hip_bfloat16* WoutT = (__hip_bfloat16*)alloc((size_t)HID * INNER * 2);
  float*          dtb   = (float*)alloc((size_t)NTOK * INNER * 4);
  float*          Bm    = (float*)alloc((size_t)NTOK * NSTATE * 4);
  float*          Cm    = (float*)alloc((size_t)NTOK * NSTATE * 4);
  float*          Pmid  = (float*)alloc((size_t)2 * NTOK * NMID * 4);        // 71MB: mid partials; later S; later out partials
  float*          A_chk = (float*)alloc((size_t)BATCH * NCHUNK * INNER * 4);

  __hip_bfloat16* x_bf   = (__hip_bfloat16*)scr;
  __hip_bfloat16* WinT   = (__hip_bfloat16*)(scr + (size_t)NTOK * HID * 2);
  __hip_bfloat16* xch    = (__hip_bfloat16*)scr;
  __hip_bfloat16* ygated = xin;
  float*          S      = Pmid;   // 64MB <= 71MB, after reduce_mid
  float*          Pout   = Pmid;   // 64MB, after scan_out

  // 1. conversions / transposes
  cvt_f32_bf16_kernel<<<(NTOK * HID / 4 + 255) / 256, 256, 0, stream>>>(x, x_bf, NTOK * HID / 4);
  transpose_cvt_kernel<<<dim3((2 * INNER) / 32, HID / 32), 256, 0, stream>>>(W_in, WinT, HID, 2 * INNER, HID);
  transpose_cvt_kernel<<<dim3(INNER / 32, INNER / 32), 256, 0, stream>>>(W_dt, WmidT, INNER, INNER, INNER);
  transpose_cvt_kernel<<<dim3(NSTATE / 32, INNER / 32), 256, 0, stream>>>(
      W_B, WmidT + (size_t)INNER * INNER, INNER, NSTATE, INNER);
  transpose_cvt_kernel<<<dim3(NSTATE / 32, INNER / 32), 256, 0, stream>>>(
      W_C, WmidT + (size_t)(INNER + NSTATE) * INNER, INNER, NSTATE, INNER);
  transpose_cvt_kernel<<<dim3(HID / 32, INNER / 32), 256, 0, stream>>>(W_out, WoutT, INNER, HID, INNER);

  // 2. xz = x @ W_in  -> split bf16 (xin | z)   [1024 blocks, 4/CU]
  {
    const int gridN = (2 * INNER) / 128, nwg = (NTOK / 128) * gridN;
    gemm_bt_kernel<1><<<nwg, 256, 0, stream>>>(
        x_bf, WinT, NTOK, 2 * INNER, HID, HID, gridN, nwg, nwg, nullptr, 0, xin, zbf);
  }

  // 3. conv + silu
  conv_silu_kernel<<<(NTOK * (INNER / 4)) / 256, 256, 0, stream>>>(xin, conv_w, conv_b, xch);

  // 4. mid GEMM split-K x2 [1088 blocks, 4.25/CU] + fused reduce/softplus
  {
    const int gridN = NMID / 128;                 // 17
    const int mnwg = (NTOK / 128) * gridN;        // 544 per part
    const int nwg = mnwg * 2;                     // 1088
    gemm_bt_kernel<0><<<nwg, 256, 0, stream>>>(
        xch, WmidT, NTOK, NMID, INNER / 2, INNER, gridN, nwg, mnwg, Pmid, NMID,
        nullptr, nullptr);
    reduce_mid_kernel<<<(NTOK * (NMID / 4)) / 256, 256, 0, stream>>>(Pmid, b_dt, dtb, Bm, Cm);
  }

  // 5. chunked selective scan (S aliases Pmid)
  scan_state_kernel<<<dim3(INNER / 256, NCHUNK, BATCH), 256, 0, stream>>>(dtb, xch, Bm, S, A_chk);
  scan_combine_kernel<<<(BATCH * INNER * NSTATE) / 256, 256, 0, stream>>>(S, A_chk);
  scan_out_kernel<<<dim3(INNER / 256, NCHUNK, BATCH), 256, 0, stream>>>(
      dtb, xch, Bm, Cm, S, zbf, Dvec, ygated);

  // 6. out = ygated @ W_out, split-K x4 [1024 blocks, 4/CU] + reduce
  {
    const int gridN = HID / 128;                  // 8
    const int mnwg = (NTOK / 128) * gridN;        // 256 per part
    const int nwg = mnwg * 4;                     // 1024
    gemm_bt_kernel<0><<<nwg, 256, 0, stream>>>(
        ygated, WoutT, NTOK, HID, INNER / 4, INNER, gridN, nwg, mnwg, Pout, HID,
        nullptr, nullptr);
    const int n4 = NTOK * HID / 4;
    reduce4_kernel<<<(n4 + 255) / 256, 256, 0, stream>>>(Pout, out, n4);
  }
}